// Round 1
// baseline (79.609 us; speedup 1.0000x reference)
//
#include <hip/hip_runtime.h>

#define HW_TOTAL (4096 * 4096)
#define NBINS 256

// ---------------------------------------------------------------------------
// Kernel 1: integer histogram of pixel values (256 bins).
// Per-block LDS with 4 sub-histograms (split by tid&3) to cut LDS atomic
// serialization, int4 vectorized global loads, one global atomicAdd per
// (bin, block) at the end.
// ---------------------------------------------------------------------------
__global__ __launch_bounds__(256) void otsu_hist_k(const int4* __restrict__ img4,
                                                   unsigned* __restrict__ ghist,
                                                   int nchunks) {
    __shared__ unsigned h[4 * NBINS];
    for (int i = threadIdx.x; i < 4 * NBINS; i += 256) h[i] = 0;
    __syncthreads();

    const unsigned sub = (threadIdx.x & 3u) << 8;
    const int stride = gridDim.x * blockDim.x;
    for (int i = blockIdx.x * blockDim.x + threadIdx.x; i < nchunks; i += stride) {
        int4 v = img4[i];
        atomicAdd(&h[sub + (unsigned)v.x], 1u);
        atomicAdd(&h[sub + (unsigned)v.y], 1u);
        atomicAdd(&h[sub + (unsigned)v.z], 1u);
        atomicAdd(&h[sub + (unsigned)v.w], 1u);
    }
    __syncthreads();

    for (int i = threadIdx.x; i < NBINS; i += 256) {
        unsigned t = h[i] + h[i + 256] + h[i + 512] + h[i + 768];
        if (t) atomicAdd(&ghist[i], t);
    }
}

// ---------------------------------------------------------------------------
// Kernel 2: Otsu threshold from the histogram. One wave (64 lanes), each lane
// owns 4 consecutive bins. Exact uint64 prefix sums (wave scan via shfl_up),
// float64 inter-class variance, argmax with first-index tiebreak.
// Writes thresh to d_out[0] and to ws (for the binarize kernel).
// ---------------------------------------------------------------------------
__global__ __launch_bounds__(64) void otsu_thresh_k(const unsigned* __restrict__ ghist,
                                                    int* __restrict__ d_out,
                                                    int* __restrict__ thresh_ws) {
    const int lane = threadIdx.x;

    uint4 c = ((const uint4*)ghist)[lane];
    unsigned cs[4] = {c.x, c.y, c.z, c.w};

    // per-lane sequential inclusive partials over its 4 bins
    unsigned long long lc[4], lv[4];
    unsigned long long ccum = 0ull, vcum = 0ull;
#pragma unroll
    for (int k = 0; k < 4; ++k) {
        ccum += cs[k];
        vcum += (unsigned long long)cs[k] * (unsigned)(4 * lane + k);
        lc[k] = ccum;
        lv[k] = vcum;
    }

    // inclusive wave scan of the per-lane totals
    unsigned long long cscan = ccum, vscan = vcum;
    for (int d = 1; d < 64; d <<= 1) {
        unsigned long long cu = __shfl_up(cscan, d);
        unsigned long long vu = __shfl_up(vscan, d);
        if (lane >= d) { cscan += cu; vscan += vu; }
    }
    const unsigned long long cbase = cscan - ccum;   // exclusive prefix
    const unsigned long long vbase = vscan - vcum;
    const unsigned long long vtotal = __shfl(vscan, 63);

    // inter-class variance in float64 (true argmax; see analysis)
    double best = -1.0;
    int bestt = 255;
    const double hw = (double)HW_TOTAL;
    const double vtot_d = (double)vtotal;
#pragma unroll
    for (int k = 0; k < 4; ++k) {
        int t = 4 * lane + k;
        if (t > 254) continue;
        double nb = (double)(cbase + lc[k]);
        double sb = (double)(vbase + lv[k]);
        double nw = hw - nb;
        double sw = vtot_d - sb;
        double mb = sb / nb;
        double mw = sw / nw;
        double dm = mb - mw;
        double var = nb * nw * dm * dm;
        if (var > best || (var == best && t < bestt)) { best = var; bestt = t; }
    }

    // butterfly argmax reduce, first-index tiebreak
    for (int d = 32; d >= 1; d >>= 1) {
        double ov = __shfl_xor(best, d);
        int ot = __shfl_xor(bestt, d);
        if (ov > best || (ov == best && ot < bestt)) { best = ov; bestt = ot; }
    }
    if (lane == 0) {
        d_out[0] = bestt;
        *thresh_ws = bestt;
    }
}

// ---------------------------------------------------------------------------
// Kernel 3: binarize. Output image lives at out[1..HW], so aligned int4
// output chunk out[4c..4c+3] corresponds to pixels 4c-1..4c+2. Pixel 4c-1
// comes from the wave neighbor via shfl_up; lane 0 does one scalar load.
// Chunk 0 re-writes out[0] = thresh. Tail pixel handled by thread 0.
// ---------------------------------------------------------------------------
__global__ __launch_bounds__(256) void otsu_bin_k(const int* __restrict__ img,
                                                  int* __restrict__ out,
                                                  const int* __restrict__ thresh_ws) {
    const int c = blockIdx.x * 256 + threadIdx.x;
    const int thresh = *thresh_ws;   // uniform scalar load

    int4 v = ((const int4*)img)[c];      // pixels 4c .. 4c+3 (aligned)
    const int lane = threadIdx.x & 63;
    int prev = __shfl_up(v.w, 1);        // pixel 4c-1 from previous lane
    if (lane == 0) prev = (c > 0) ? img[4 * c - 1] : 0;

    int4 o;
    o.x = (c == 0) ? thresh : ((prev <= thresh) ? 0 : 256);
    o.y = (v.x <= thresh) ? 0 : 256;
    o.z = (v.y <= thresh) ? 0 : 256;
    o.w = (v.z <= thresh) ? 0 : 256;
    ((int4*)out)[c] = o;                 // 16B-aligned store

    if (c == 0) {
        // out index HW_TOTAL = image pixel HW_TOTAL-1 (tail of shifted layout)
        out[HW_TOTAL] = (img[HW_TOTAL - 1] <= thresh) ? 0 : 256;
    }
}

extern "C" void kernel_launch(void* const* d_in, const int* in_sizes, int n_in,
                              void* d_out, int out_size, void* d_ws, size_t ws_size,
                              hipStream_t stream) {
    const int* img = (const int*)d_in[0];
    int* out = (int*)d_out;
    unsigned* ghist = (unsigned*)d_ws;
    int* thresh_ws = (int*)d_ws + NBINS;

    // zero the histogram every call (ws is poisoned once, never re-poisoned)
    hipMemsetAsync(d_ws, 0, NBINS * sizeof(unsigned), stream);

    const int nchunks = HW_TOTAL / 4;                 // int4 chunks
    otsu_hist_k<<<2048, 256, 0, stream>>>((const int4*)img, ghist, nchunks);
    otsu_thresh_k<<<1, 64, 0, stream>>>(ghist, out, thresh_ws);
    otsu_bin_k<<<HW_TOTAL / 4 / 256, 256, 0, stream>>>(img, out, thresh_ws);
}

// Round 2
// 45.830 us; speedup vs baseline: 1.7371x; 1.7371x over previous
//
#include <hip/hip_runtime.h>

#define HW_TOTAL (4096 * 4096)
#define NBINS 256
#define NCHUNK (HW_TOTAL / 4)      // int4 chunks = 4M
#define HIST_B 512                 // histogram blocks
#define CH_PER_BLK (NCHUNK / HIST_B)   // 8192 chunks per block
#define BATCH 8                    // int4 loads in flight per thread
#define BIN_COARSEN 4
#define BIN_B (NCHUNK / 256 / BIN_COARSEN)  // 4096 blocks

// ws layout: [0] thresh (int), +256B: partials (HIST_B*NBINS u32) or ghist (NBINS u32)
#define WS_PART_BYTES (HIST_B * NBINS * 4 + 256)

// ---------------------------------------------------------------------------
// Kernel 1: histogram. Per-block LDS with 4 sub-histograms (split by tid&3 to
// cut same-address atomic serialization). Batched loads: 8 independent int4
// loads issued before use -> 8 in flight per thread (fixes latency-boundness).
// MODE 0: store per-block partial to ws (no global atomics, no memset needed).
// MODE 1: global atomicAdd flush (fallback when ws is small).
// ---------------------------------------------------------------------------
template <int MODE>
__global__ __launch_bounds__(256) void otsu_hist_k(const int4* __restrict__ img4,
                                                   unsigned* __restrict__ out) {
    __shared__ unsigned h[4 * NBINS];
    for (int i = threadIdx.x; i < 4 * NBINS; i += 256) h[i] = 0;
    __syncthreads();

    const unsigned sub = (threadIdx.x & 3u) << 8;
    const int base = blockIdx.x * CH_PER_BLK;

    for (int ob = 0; ob < CH_PER_BLK / (256 * BATCH); ++ob) {
        int4 v[BATCH];
        const int i0 = base + ob * (256 * BATCH) + threadIdx.x;
#pragma unroll
        for (int k = 0; k < BATCH; ++k) v[k] = img4[i0 + k * 256];
#pragma unroll
        for (int k = 0; k < BATCH; ++k) {
            atomicAdd(&h[sub + (unsigned)v[k].x], 1u);
            atomicAdd(&h[sub + (unsigned)v[k].y], 1u);
            atomicAdd(&h[sub + (unsigned)v[k].z], 1u);
            atomicAdd(&h[sub + (unsigned)v[k].w], 1u);
        }
    }
    __syncthreads();

    // flush: 256 threads, one bin each
    const int i = threadIdx.x;
    unsigned t = h[i] + h[i + 256] + h[i + 512] + h[i + 768];
    if (MODE == 0) {
        out[blockIdx.x * NBINS + i] = t;
    } else {
        if (t) atomicAdd(&out[i], t);
    }
}

// ---------------------------------------------------------------------------
// Kernel 2: reduce partials + Otsu threshold. 1024 threads: thread (bin, q)
// sums partial histograms b in [q*BQ, (q+1)*BQ). Then wave 0 does exact
// uint64 prefix scan (shfl) + float64 inter-class variance argmax.
// val_sum[t] == t * cnt[t] exactly, so only the count histogram is needed.
// ---------------------------------------------------------------------------
__global__ __launch_bounds__(1024) void otsu_thresh_k(const unsigned* __restrict__ partials,
                                                      int B,
                                                      int* __restrict__ d_out,
                                                      int* __restrict__ thresh_ws) {
    __shared__ unsigned part[4][NBINS];
    __shared__ unsigned cnt[NBINS];

    const int bin = threadIdx.x & 255;
    const int q = threadIdx.x >> 8;
    const int BQ = (B + 3) / 4;
    int b = q * BQ;
    int e = min((q + 1) * BQ, B);
    unsigned s = 0;
    for (; b + 8 <= e; b += 8) {
#pragma unroll
        for (int k = 0; k < 8; ++k) s += partials[(b + k) * NBINS + bin];
    }
    for (; b < e; ++b) s += partials[b * NBINS + bin];
    part[q][bin] = s;
    __syncthreads();

    if (threadIdx.x < 256)
        cnt[bin] = part[0][bin] + part[1][bin] + part[2][bin] + part[3][bin];
    __syncthreads();

    if (threadIdx.x >= 64) return;
    const int lane = threadIdx.x;

    uint4 c = ((const uint4*)cnt)[lane];
    unsigned cs[4] = {c.x, c.y, c.z, c.w};

    unsigned long long lc[4], lv[4];
    unsigned long long ccum = 0ull, vcum = 0ull;
#pragma unroll
    for (int k = 0; k < 4; ++k) {
        ccum += cs[k];
        vcum += (unsigned long long)cs[k] * (unsigned)(4 * lane + k);
        lc[k] = ccum;
        lv[k] = vcum;
    }

    unsigned long long cscan = ccum, vscan = vcum;
    for (int d = 1; d < 64; d <<= 1) {
        unsigned long long cu = __shfl_up(cscan, d);
        unsigned long long vu = __shfl_up(vscan, d);
        if (lane >= d) { cscan += cu; vscan += vu; }
    }
    const unsigned long long cbase = cscan - ccum;
    const unsigned long long vbase = vscan - vcum;
    const unsigned long long vtotal = __shfl(vscan, 63);

    double best = -1.0;
    int bestt = 255;
    const double hw = (double)HW_TOTAL;
    const double vtot_d = (double)vtotal;
#pragma unroll
    for (int k = 0; k < 4; ++k) {
        int t = 4 * lane + k;
        if (t > 254) continue;
        double nb = (double)(cbase + lc[k]);
        double sb = (double)(vbase + lv[k]);
        double nw = hw - nb;
        double sw = vtot_d - sb;
        double mb = sb / nb;
        double mw = sw / nw;
        double dm = mb - mw;
        double var = nb * nw * dm * dm;
        if (var > best || (var == best && t < bestt)) { best = var; bestt = t; }
    }

    for (int d = 32; d >= 1; d >>= 1) {
        double ov = __shfl_xor(best, d);
        int ot = __shfl_xor(bestt, d);
        if (ov > best || (ov == best && ot < bestt)) { best = ov; bestt = ot; }
    }
    if (lane == 0) {
        d_out[0] = bestt;
        *thresh_ws = bestt;
    }
}

// ---------------------------------------------------------------------------
// Kernel 3: binarize, 4 chunks per thread. Output image lives at out[1..HW],
// so aligned out-chunk out[4c..4c+3] = bin of pixels 4c-1..4c+2. Pixel 4c-1
// comes from the wave neighbor via shfl_up (lane 0: one scalar load).
// ---------------------------------------------------------------------------
__global__ __launch_bounds__(256) void otsu_bin_k(const int* __restrict__ img,
                                                  int* __restrict__ out,
                                                  const int* __restrict__ thresh_ws) {
    const int thresh = *thresh_ws;
    const int base = blockIdx.x * (256 * BIN_COARSEN);
    const int lane = threadIdx.x & 63;
#pragma unroll
    for (int k = 0; k < BIN_COARSEN; ++k) {
        const int c = base + k * 256 + threadIdx.x;
        int4 v = ((const int4*)img)[c];
        int prev = __shfl_up(v.w, 1);
        if (lane == 0) prev = (c > 0) ? img[4 * c - 1] : 0;
        int4 o;
        o.x = (c == 0) ? thresh : ((prev <= thresh) ? 0 : 256);
        o.y = (v.x <= thresh) ? 0 : 256;
        o.z = (v.y <= thresh) ? 0 : 256;
        o.w = (v.z <= thresh) ? 0 : 256;
        ((int4*)out)[c] = o;
    }
    if (blockIdx.x == 0 && threadIdx.x == 0)
        out[HW_TOTAL] = (img[HW_TOTAL - 1] <= thresh) ? 0 : 256;
}

extern "C" void kernel_launch(void* const* d_in, const int* in_sizes, int n_in,
                              void* d_out, int out_size, void* d_ws, size_t ws_size,
                              hipStream_t stream) {
    const int* img = (const int*)d_in[0];
    int* out = (int*)d_out;
    int* thresh_ws = (int*)d_ws;                       // ws[0]
    unsigned* hist_buf = (unsigned*)((char*)d_ws + 256);

    if (ws_size >= WS_PART_BYTES) {
        // partial-histogram scheme: no global atomics, no memset
        otsu_hist_k<0><<<HIST_B, 256, 0, stream>>>((const int4*)img, hist_buf);
        otsu_thresh_k<<<1, 1024, 0, stream>>>(hist_buf, HIST_B, out, thresh_ws);
    } else {
        // fallback: atomic flush into a single 256-bin histogram
        hipMemsetAsync(hist_buf, 0, NBINS * sizeof(unsigned), stream);
        otsu_hist_k<1><<<HIST_B, 256, 0, stream>>>((const int4*)img, hist_buf);
        otsu_thresh_k<<<1, 1024, 0, stream>>>(hist_buf, 1, out, thresh_ws);
    }
    otsu_bin_k<<<BIN_B, 256, 0, stream>>>(img, out, thresh_ws);
}